// Round 4
// baseline (1431.256 us; speedup 1.0000x reference)
//
#include <hip/hip_runtime.h>

#define CH   2048
#define COLS 128          // N*H = 4*32
#define WDIM 48
#define SL   (COLS*CH)    // 262144 elems per w-slice
#define NWG  128
#define TPB  512

using f32x16 = __attribute__((ext_vector_type(16))) float;
using bf16x8 = __attribute__((ext_vector_type(8))) short;

__device__ __forceinline__ short f2bf(float f) {
    union { float f; unsigned u; } v; v.f = f;
    unsigned u = v.u;
    u += 0x7fffu + ((u >> 16) & 1u);   // round-to-nearest-even
    return (short)(u >> 16);
}

// Wc bf16 from conv_w fp32 (C,C,1,9) taking [:,:,0,4]
__global__ __launch_bounds__(256) void prep_w(const float* __restrict__ cw,
                                              short* __restrict__ wcb) {
    int idx = blockIdx.x * 256 + threadIdx.x;          // o*2048 + c
    wcb[idx] = f2bf(cw[(size_t)idx * 9 + 4]);
}

// feature (N,C,H,W) -> x_t[w][col][c], col = n*32 + h
__global__ __launch_bounds__(256) void prep_x(const float* __restrict__ feat,
                                              float* __restrict__ xt) {
    int b = blockIdx.x;
    int col = b >> 5;            // 0..127
    int ct  = b & 31;            // c-tile (64 channels)
    int n = col >> 5, h = col & 31;
    int c0 = ct * 64;
    __shared__ float tile[64][49];
    int t = threadIdx.x;
    const float* base = feat + (((size_t)n * CH + c0) * 32 + h) * WDIM;
    #pragma unroll
    for (int it = 0; it < 3; ++it) {
        int id = it * 256 + t;             // 0..767
        int row = id / 12, w4 = id % 12;
        float4 v = *reinterpret_cast<const float4*>(base + (size_t)row * 1536 + w4 * 4);
        tile[row][w4*4+0] = v.x; tile[row][w4*4+1] = v.y;
        tile[row][w4*4+2] = v.z; tile[row][w4*4+3] = v.w;
    }
    __syncthreads();
    int c = t & 63, wq = t >> 6;
    #pragma unroll
    for (int it = 0; it < 12; ++it) {
        int w = it * 4 + wq;
        xt[((size_t)w * COLS + col) * CH + c0 + c] = tile[c][w];
    }
}

__global__ __launch_bounds__(256) void init0_k(const float* __restrict__ x0,
                                               float* __restrict__ fl0,
                                               short* __restrict__ fb0) {
    int i = blockIdx.x * 256 + threadIdx.x;
    float v = x0[i];
    fl0[i] = v;
    fb0[i] = f2bf(v);
}

// Persistent kernel: 128 WGs, each runs TWO independent col-chains (cg=p, p+2)
// interleaved so each chain's barrier propagation hides under the other
// chain's compute. B fragments prefetched one phase ahead into registers.
__global__ __launch_bounds__(TPB, 1) void persist_k(
        const short* __restrict__ wcb, const float* __restrict__ xt,
        short* __restrict__ flbf, short* __restrict__ bwdb,
        float* __restrict__ fl32, float* __restrict__ outt,
        const float* __restrict__ bias, const float* __restrict__ pa,
        unsigned* __restrict__ cnt, int byp)
{
    __shared__ short lA[8 * 4096];        // 64 KB: A high-K half, frag-linear
    __shared__ float red[8 * 16 * 64];    // 32 KB: single-phase K-split reduce
    __shared__ short sst[32 * 34 + 8];    // 2.2 KB: padded state transpose

    int wg = blockIdx.x;
    int p = wg & 1, mg = wg >> 1;
    int m0 = mg * 32;
    int cgA = p, cgB = p + 2;             // two independent chains
    int t = threadIdx.x;
    int wv = t >> 6, l = t & 63;
    int lrow = l & 31, lhalf = l >> 5;

    // A panel: per wave K-range [wv*256, wv*256+256): low 128 in VGPRs, high 128 in LDS
    bf16x8 aR[8];
    {
        const short* s0 = wcb + (size_t)(m0 + lrow) * CH + wv * 256 + 8 * lhalf;
        #pragma unroll
        for (int kk = 0; kk < 8; ++kk)
            aR[kk] = *reinterpret_cast<const bf16x8*>(s0 + kk * 16);
        const short* s1 = s0 + 128;
        short* dst = lA + wv * 4096 + l * 8;
        #pragma unroll
        for (int kk = 0; kk < 8; ++kk)
            *reinterpret_cast<bf16x8*>(dst + kk * 512) =
                *reinterpret_cast<const bf16x8*>(s1 + kk * 16);
    }
    const short* aL = lA + wv * 4096 + l * 8;

    // Step-invariant epilogue constants
    int rr = t >> 6, le = t & 63;
    int col = le & 31;
    int row0 = (rr & 3) + 8 * (rr >> 2) + 4 * (le >> 5);
    int o0 = m0 + row0, o1 = o0 + 16;
    float b0 = bias[o0], b1 = bias[o1];
    float aP = *pa;
    int scol = t >> 4, sj = t & 15;

    int n0A = cgA * 32, n0B = cgB * 32;
    size_t off0A = (size_t)(n0A + col) * CH + o0;
    size_t off1A = (size_t)(n0A + col) * CH + o1;
    size_t off0B = (size_t)(n0B + col) * CH + o0;
    size_t off1B = (size_t)(n0B + col) * CH + o1;
    size_t soffA = (((size_t)(n0A + scol) * CH + m0) >> 1) + sj;
    size_t soffB = (((size_t)(n0B + scol) * CH + m0) >> 1) + sj;
    size_t boffA = (size_t)(n0A + lrow) * CH + wv * 256 + 8 * lhalf;
    size_t boffB = (size_t)(n0B + lrow) * CH + wv * 256 + 8 * lhalf;

    auto arrive = [&](int cg_) {
        __syncthreads();                  // drains every wave's stores (vmcnt 0)
        if (t == 0)
            __hip_atomic_fetch_add(cnt + (cg_ * 4 + (mg & 3)) * 32, 1u,
                                   __ATOMIC_RELAXED, __HIP_MEMORY_SCOPE_AGENT);
    };
    auto waitbar = [&](int cg_, unsigned steps) {
        unsigned tgt = steps * 16u;       // 16 WGs per sub-counter per step
        unsigned* base = cnt + cg_ * 128;
        int guard = 0;
        for (;;) {
            unsigned v = __hip_atomic_load(base + (l & 3) * 32,
                                           __ATOMIC_RELAXED, __HIP_MEMORY_SCOPE_AGENT);
            if (__all((int)(v >= tgt))) break;
            __builtin_amdgcn_s_sleep(2);
            if (++guard > (1 << 16)) break;     // fail visibly, never hang
        }
    };

    auto Lload = [&](bf16x8* bq, const short* prevb, size_t boff) {
        const short* bp = prevb + boff;
        #pragma unroll
        for (int kk = 0; kk < 16; ++kk)
            bq[kk] = *reinterpret_cast<const bf16x8*>(bp + kk * 16);
    };
    auto LloadByp = [&](bf16x8* bq, const short* prevb, size_t boff) {
        const int* ip = reinterpret_cast<const int*>(prevb + boff);
        #pragma unroll
        for (int kk = 0; kk < 16; ++kk) {
            union { int i4[4]; bf16x8 v; } u;
            #pragma unroll
            for (int j = 0; j < 4; ++j)
                u.i4[j] = __hip_atomic_load(const_cast<int*>(ip) + kk * 4 + j,
                                            __ATOMIC_RELAXED, __HIP_MEMORY_SCOPE_AGENT);
            bq[kk] = u.v;
        }
    };

    auto Cphase = [&](bf16x8* bq, const float* res, float* outf, int* outb_i,
                      size_t off0_, size_t off1_, size_t soff_, float* extra) {
        float r0 = res[off0_], r1 = res[off1_];
        f32x16 acc = {};
        #pragma unroll
        for (int kk = 0; kk < 8; ++kk)
            acc = __builtin_amdgcn_mfma_f32_32x32x16_bf16(aR[kk], bq[kk], acc, 0, 0, 0);
        #pragma unroll
        for (int kk = 0; kk < 8; ++kk) {
            bf16x8 af = *reinterpret_cast<const bf16x8*>(aL + kk * 512);
            acc = __builtin_amdgcn_mfma_f32_32x32x16_bf16(af, bq[8 + kk], acc, 0, 0, 0);
        }
        #pragma unroll
        for (int r = 0; r < 16; ++r) red[(wv * 16 + r) * 64 + l] = acc[r];
        __syncthreads();
        float s0 = 0.f, s1 = 0.f;
        #pragma unroll
        for (int w2 = 0; w2 < 8; ++w2) {
            s0 += red[(w2 * 16 + rr) * 64 + le];
            s1 += red[(w2 * 16 + rr + 8) * 64 + le];
        }
        float v0 = s0 + b0; v0 = (v0 >= 0.f) ? v0 : aP * v0; v0 += r0;
        float v1 = s1 + b1; v1 = (v1 >= 0.f) ? v1 : aP * v1; v1 += r1;
        outf[off0_] = v0; outf[off1_] = v1;
        if (extra) { extra[off0_] = v0; extra[off1_] = v1; }
        if (outb_i) {
            sst[col * 34 + row0] = f2bf(v0);        // stride 34: conflict-free
            sst[col * 34 + row0 + 16] = f2bf(v1);
            __syncthreads();
            int sv = *reinterpret_cast<const int*>(&sst[scol * 34 + 2 * sj]);
            __hip_atomic_store(outb_i + soff_, sv,
                               __ATOMIC_RELAXED, __HIP_MEMORY_SCOPE_AGENT);
        }
    };

    unsigned scA = 0, scB = 0;
    bf16x8 bqA[16], bqB[16];

    // prologue: state 0 from init0_k (prior dispatch -> visible, no barrier)
    Lload(bqA, flbf, boffA);
    Lload(bqB, flbf, boffB);

    // ---- forward: fl[w] = prelu(Wc@fl[w-1]+b) + x[w] ----
    for (int w = 1; w <= 47; ++w) {
        float* ex = (w == 47) ? (outt + (size_t)47 * SL) : nullptr;
        Cphase(bqA, xt + (size_t)w * SL, fl32 + (size_t)w * SL,
               reinterpret_cast<int*>(flbf + (size_t)w * SL),
               off0A, off1A, soffA, ex);
        arrive(cgA); ++scA;
        waitbar(cgA, scA);
        Lload(bqA, flbf + (size_t)w * SL, boffA);   // w<47: next fwd; w==47: bwd i=46

        Cphase(bqB, xt + (size_t)w * SL, fl32 + (size_t)w * SL,
               reinterpret_cast<int*>(flbf + (size_t)w * SL),
               off0B, off1B, soffB, ex);
        arrive(cgB); ++scB;
        waitbar(cgB, scB);
        Lload(bqB, flbf + (size_t)w * SL, boffB);
    }

    // ---- backward: out[i] = prelu(Wc@state+b) + fl[i] ----
    for (int i = 46; i >= 0; --i) {
        short* nxt = bwdb + (size_t)(byp ? (i & 1) : i) * SL;
        Cphase(bqA, fl32 + (size_t)i * SL, outt + (size_t)i * SL,
               (i > 0) ? reinterpret_cast<int*>(nxt) : nullptr,
               off0A, off1A, soffA, nullptr);
        if (i > 0) {
            arrive(cgA); ++scA; waitbar(cgA, scA);
            if (byp) LloadByp(bqA, nxt, boffA); else Lload(bqA, nxt, boffA);
        }
        Cphase(bqB, fl32 + (size_t)i * SL, outt + (size_t)i * SL,
               (i > 0) ? reinterpret_cast<int*>(nxt) : nullptr,
               off0B, off1B, soffB, nullptr);
        if (i > 0) {
            arrive(cgB); ++scB; waitbar(cgB, scB);
            if (byp) LloadByp(bqB, nxt, boffB); else Lload(bqB, nxt, boffB);
        }
    }
}

// out_t[w][col][c] -> dout (N,C,H,W)
__global__ __launch_bounds__(256) void fin_t(const float* __restrict__ ot,
                                             float* __restrict__ dout) {
    int b = blockIdx.x;
    int col = b >> 5, ct = b & 31;
    int n = col >> 5, h = col & 31;
    int c0 = ct * 64;
    __shared__ float tile[48][65];
    int t = threadIdx.x;
    int c = t & 63, wq = t >> 6;
    #pragma unroll
    for (int it = 0; it < 12; ++it) {
        int w = it * 4 + wq;
        tile[w][c] = ot[((size_t)w * COLS + col) * CH + c0 + c];
    }
    __syncthreads();
    float* base = dout + (((size_t)n * CH + c0) * 32 + h) * WDIM;
    #pragma unroll
    for (int it = 0; it < 3; ++it) {
        int id = it * 256 + t;
        int row = id / 12, w4 = id % 12;
        float4 v;
        v.x = tile[w4*4+0][row]; v.y = tile[w4*4+1][row];
        v.z = tile[w4*4+2][row]; v.w = tile[w4*4+3][row];
        *reinterpret_cast<float4*>(base + (size_t)row * 1536 + w4 * 4) = v;
    }
}

extern "C" void kernel_launch(void* const* d_in, const int* in_sizes, int n_in,
                              void* d_out, int out_size, void* d_ws, size_t ws_size,
                              hipStream_t stream) {
    const float* feat = (const float*)d_in[0];
    const float* cw   = (const float*)d_in[1];
    const float* bias = (const float*)d_in[2];
    const float* pa   = (const float*)d_in[3];

    float* fl32 = (float*)d_out;                 // 48 fp32 slices live in d_out

    char* ws = (char*)d_ws;
    short* wcb  = (short*)(ws);                  // 8 MB    bf16 Wc
    float* xt   = (float*)(ws + 8388608);        // 48 MB   x_t (reused as out_t)
    short* flbf = (short*)(ws + 58720256);       // 24 MB   bf16 forward states (48 slices)
    unsigned* cnt = (unsigned*)(ws + 83886080);  // 2 KB    per-chain sub-counters
    short* bwdb = (short*)(ws + 83888128);       // 23.5 MB backward states (47 slices)
    float* outt = xt;

    // Full per-step bwd slices need ws >= ~108.6 MB; else ping-pong + bypass loads.
    const size_t needed_full = 83888128ull + 47ull * SL * 2;
    int byp = (ws_size < needed_full) ? 1 : 0;

    hipMemsetAsync(cnt, 0, 2048, stream);
    prep_w<<<16384, 256, 0, stream>>>(cw, wcb);
    prep_x<<<4096, 256, 0, stream>>>(feat, xt);
    init0_k<<<1024, 256, 0, stream>>>(xt, fl32, flbf);   // fl[0] = x[0]

    persist_k<<<NWG, TPB, 0, stream>>>(wcb, xt, flbf, bwdb, fl32, outt,
                                       bias, pa, cnt, byp);

    fin_t<<<4096, 256, 0, stream>>>(outt, (float*)d_out);
}

// Round 5
// 431.402 us; speedup vs baseline: 3.3177x; 3.3177x over previous
//
#include <hip/hip_runtime.h>

#define CH   2048
#define COLS 128          // N*H = 4*32
#define WDIM 48
#define SL   (COLS*CH)    // 262144 elems per w-slice
#define NWG  256
#define TPB  512

using f32x4  = __attribute__((ext_vector_type(4))) float;
using bf16x8 = __attribute__((ext_vector_type(8))) short;

__device__ __forceinline__ short f2bf(float f) {
    union { float f; unsigned u; } v; v.f = f;
    unsigned u = v.u;
    u += 0x7fffu + ((u >> 16) & 1u);   // round-to-nearest-even
    return (short)(u >> 16);
}

// Wc bf16 from conv_w fp32 (C,C,1,9) taking [:,:,0,4]
__global__ __launch_bounds__(256) void prep_w(const float* __restrict__ cw,
                                              short* __restrict__ wcb) {
    int idx = blockIdx.x * 256 + threadIdx.x;          // o*2048 + c
    wcb[idx] = f2bf(cw[(size_t)idx * 9 + 4]);
}

// feature (N,C,H,W) -> x_t[w][col][c], col = n*32 + h
__global__ __launch_bounds__(256) void prep_x(const float* __restrict__ feat,
                                              float* __restrict__ xt) {
    int b = blockIdx.x;
    int col = b >> 5;            // 0..127
    int ct  = b & 31;            // c-tile (64 channels)
    int n = col >> 5, h = col & 31;
    int c0 = ct * 64;
    __shared__ float tile[64][49];
    int t = threadIdx.x;
    const float* base = feat + (((size_t)n * CH + c0) * 32 + h) * WDIM;
    #pragma unroll
    for (int it = 0; it < 3; ++it) {
        int id = it * 256 + t;             // 0..767
        int row = id / 12, w4 = id % 12;
        float4 v = *reinterpret_cast<const float4*>(base + (size_t)row * 1536 + w4 * 4);
        tile[row][w4*4+0] = v.x; tile[row][w4*4+1] = v.y;
        tile[row][w4*4+2] = v.z; tile[row][w4*4+3] = v.w;
    }
    __syncthreads();
    int c = t & 63, wq = t >> 6;
    #pragma unroll
    for (int it = 0; it < 12; ++it) {
        int w = it * 4 + wq;
        xt[((size_t)w * COLS + col) * CH + c0 + c] = tile[c][w];
    }
}

__global__ __launch_bounds__(256) void init0_k(const float* __restrict__ x0,
                                               float* __restrict__ fl0,
                                               short* __restrict__ fb0) {
    int i = blockIdx.x * 256 + threadIdx.x;
    float v = x0[i];
    fl0[i] = v;
    fb0[i] = f2bf(v);
}

// Persistent kernel: 256 WGs = 8 self-contained groups of 32.
// Group g = wg&7 owns cols [g*16, g*16+16) of chain g>>1 for ALL 94 steps:
// its 32 WGs produce all 2048 rows -> barrier is group-local (32 flags).
// Each WG: M=64 x N=16 tile, A panel (64x2048 bf16) in 128 VGPRs/thread,
// 8 waves K-split (K=256 each), mfma_f32_16x16x32_bf16.
__global__ __launch_bounds__(TPB, 1) void persist_k(
        const short* __restrict__ wcb, const float* __restrict__ xt,
        short* __restrict__ flbf, short* __restrict__ bwdb,
        float* __restrict__ fl32, float* __restrict__ outt,
        const float* __restrict__ bias, const float* __restrict__ pa,
        unsigned* flags, int byp)
{
    __shared__ float red[8 * 16 * 65];     // 33.3 KB padded K-split reduce
    __shared__ short sst[16 * 68];         // 2.2 KB  state-store transpose

    int wg = blockIdx.x;
    int grp = wg & 7;                      // (chain, n-half); == XCD under default RR
    int mg  = wg >> 3;                     // 0..31 M-tile
    int n0 = grp * 16;                     // global col base
    int m0 = mg * 64;                      // global row base
    int t = threadIdx.x;
    int wv = t >> 6, l = t & 63;
    int lc = l & 15;                       // fragment row/col
    int lg = l >> 4;                       // k-subgroup 0..3

    // A panel into registers: aR[rb][ks], row = m0+rb*16+lc, k = wv*256+ks*32+8*lg
    bf16x8 aR[4][8];
    {
        const short* ab = wcb + (size_t)(m0 + lc) * CH + wv * 256 + 8 * lg;
        #pragma unroll
        for (int rb = 0; rb < 4; ++rb)
            #pragma unroll
            for (int ks = 0; ks < 8; ++ks)
                aR[rb][ks] = *reinterpret_cast<const bf16x8*>(ab + (size_t)rb * 16 * CH + ks * 32);
    }

    // Outputs: o0 = t (slot wv), o1 = t+512 (slot wv+8); row = rb*16+lg*4+reg
    int rb0 = wv >> 2, reg = wv & 3;
    int row0 = rb0 * 16 + lg * 4 + reg;    // o1 row = row0+32
    size_t off0 = (size_t)(n0 + lc) * CH + m0 + row0;
    size_t off1 = off0 + 32;
    float b0 = bias[m0 + row0], b1 = bias[m0 + row0 + 32];
    float aP = *pa;
    size_t soff = (((size_t)(n0 + (t >> 5)) * CH + m0) >> 1) + (t & 31);
    size_t boffs = (size_t)(n0 + lc) * CH + wv * 256 + 8 * lg;

    unsigned* gflags = flags + grp * 64;   // 32 used per group

    auto waitflags = [&](unsigned sc) {
        int guard = 0;
        for (;;) {
            unsigned v = __hip_atomic_load(gflags + (l & 31),
                                           __ATOMIC_RELAXED, __HIP_MEMORY_SCOPE_AGENT);
            if (__all((int)(v >= sc))) break;
            __builtin_amdgcn_s_sleep(1);
            if (++guard > (1 << 20)) break;          // fail visibly, never hang
        }
    };
    auto post = [&](unsigned sc) {
        __syncthreads();                   // drains all waves' vmcnt (sc1 acks)
        if (t == 0)
            __hip_atomic_store(gflags + mg, sc,
                               __ATOMIC_RELAXED, __HIP_MEMORY_SCOPE_AGENT);
    };

    float lastv0 = 0.f, lastv1 = 0.f;

    auto step = [&](const short* prevb, const float* res, float* outf,
                    short* outb, bool dostate, bool bypass, unsigned scwait) {
        float r0 = res[off0], r1 = res[off1];        // prefetch under poll
        if (scwait) waitflags(scwait);
        bf16x8 bq[8];
        const short* bp = prevb + boffs;
        if (!bypass) {
            #pragma unroll
            for (int ks = 0; ks < 8; ++ks)
                bq[ks] = *reinterpret_cast<const bf16x8*>(bp + ks * 32);
        } else {
            #pragma unroll
            for (int ks = 0; ks < 8; ++ks) {
                union { int i4[4]; bf16x8 v; } u;
                const int* ip = reinterpret_cast<const int*>(bp + ks * 32);
                #pragma unroll
                for (int j = 0; j < 4; ++j)
                    u.i4[j] = __hip_atomic_load(const_cast<int*>(ip) + j,
                                                __ATOMIC_RELAXED, __HIP_MEMORY_SCOPE_AGENT);
                bq[ks] = u.v;
            }
        }
        f32x4 acc[4] = {};
        #pragma unroll
        for (int ks = 0; ks < 8; ++ks)
            #pragma unroll
            for (int rb = 0; rb < 4; ++rb)
                acc[rb] = __builtin_amdgcn_mfma_f32_16x16x32_bf16(
                              aR[rb][ks], bq[ks], acc[rb], 0, 0, 0);
        #pragma unroll
        for (int rb = 0; rb < 4; ++rb)
            #pragma unroll
            for (int rg = 0; rg < 4; ++rg)
                red[wv * 1040 + (rb * 4 + rg) * 65 + l] = acc[rb][rg];
        __syncthreads();
        float s0 = 0.f, s1 = 0.f;
        #pragma unroll
        for (int w2 = 0; w2 < 8; ++w2) {
            s0 += red[w2 * 1040 + wv * 65 + l];
            s1 += red[w2 * 1040 + (wv + 8) * 65 + l];
        }
        float v0 = s0 + b0; v0 = (v0 >= 0.f) ? v0 : aP * v0; v0 += r0;
        float v1 = s1 + b1; v1 = (v1 >= 0.f) ? v1 : aP * v1; v1 += r1;
        outf[off0] = v0; outf[off1] = v1;
        lastv0 = v0; lastv1 = v1;
        if (dostate) {
            sst[lc * 68 + row0]      = f2bf(v0);
            sst[lc * 68 + row0 + 32] = f2bf(v1);
            __syncthreads();
            int sv = reinterpret_cast<const int*>(sst)[(t >> 5) * 34 + (t & 31)];
            __hip_atomic_store(reinterpret_cast<int*>(outb) + soff, sv,
                               __ATOMIC_RELAXED, __HIP_MEMORY_SCOPE_AGENT);
        }
    };

    // ---- forward: fl[w] = prelu(Wc@fl[w-1]+b) + x[w] ----
    for (int w = 1; w <= 47; ++w) {
        step(flbf + (size_t)(w - 1) * SL, xt + (size_t)w * SL,
             fl32 + (size_t)w * SL, flbf + (size_t)w * SL,
             true, false, (unsigned)(w - 1));
        post((unsigned)w);
    }
    // out[47] = fl[47]
    outt[(size_t)47 * SL + off0] = lastv0;
    outt[(size_t)47 * SL + off1] = lastv1;
    // ---- backward: out[i] = prelu(Wc@state+b) + fl[i] ----
    const short* prev = flbf + (size_t)47 * SL;
    unsigned sc = 47;
    for (int i = 46; i >= 0; --i) {
        short* nxt = bwdb + (size_t)(byp ? (i & 1) : i) * SL;
        bool st = (i > 0);
        step(prev, fl32 + (size_t)i * SL, outt + (size_t)i * SL,
             nxt, st, byp && (i < 46), sc);
        if (st) { ++sc; post(sc); }
        prev = nxt;
    }
}

// out_t[w][col][c] -> dout (N,C,H,W)
__global__ __launch_bounds__(256) void fin_t(const float* __restrict__ ot,
                                             float* __restrict__ dout) {
    int b = blockIdx.x;
    int col = b >> 5, ct = b & 31;
    int n = col >> 5, h = col & 31;
    int c0 = ct * 64;
    __shared__ float tile[48][65];
    int t = threadIdx.x;
    int c = t & 63, wq = t >> 6;
    #pragma unroll
    for (int it = 0; it < 12; ++it) {
        int w = it * 4 + wq;
        tile[w][c] = ot[((size_t)w * COLS + col) * CH + c0 + c];
    }
    __syncthreads();
    float* base = dout + (((size_t)n * CH + c0) * 32 + h) * WDIM;
    #pragma unroll
    for (int it = 0; it < 3; ++it) {
        int id = it * 256 + t;
        int row = id / 12, w4 = id % 12;
        float4 v;
        v.x = tile[w4*4+0][row]; v.y = tile[w4*4+1][row];
        v.z = tile[w4*4+2][row]; v.w = tile[w4*4+3][row];
        *reinterpret_cast<float4*>(base + (size_t)row * 1536 + w4 * 4) = v;
    }
}

extern "C" void kernel_launch(void* const* d_in, const int* in_sizes, int n_in,
                              void* d_out, int out_size, void* d_ws, size_t ws_size,
                              hipStream_t stream) {
    const float* feat = (const float*)d_in[0];
    const float* cw   = (const float*)d_in[1];
    const float* bias = (const float*)d_in[2];
    const float* pa   = (const float*)d_in[3];

    float* fl32 = (float*)d_out;                 // 48 fp32 slices live in d_out

    char* ws = (char*)d_ws;
    short* wcb  = (short*)(ws);                  // 8 MB    bf16 Wc
    float* xt   = (float*)(ws + 8388608);        // 48 MB   x_t (reused as out_t)
    short* flbf = (short*)(ws + 58720256);       // 24 MB   bf16 forward states (48 slices)
    unsigned* flags = (unsigned*)(ws + 83886080);// 2 KB    per-group WG flags
    short* bwdb = (short*)(ws + 83888128);       // 23.5 MB backward states (47 slices)
    float* outt = xt;

    const size_t needed_full = 83888128ull + 47ull * SL * 2;
    int byp = (ws_size < needed_full) ? 1 : 0;

    hipMemsetAsync(flags, 0, 2048, stream);
    prep_w<<<16384, 256, 0, stream>>>(cw, wcb);
    prep_x<<<4096, 256, 0, stream>>>(feat, xt);
    init0_k<<<1024, 256, 0, stream>>>(xt, fl32, flbf);   // fl[0] = x[0]

    persist_k<<<NWG, TPB, 0, stream>>>(wcb, xt, flbf, bwdb, fl32, outt,
                                       bias, pa, flags, byp);

    fin_t<<<4096, 256, 0, stream>>>(outt, (float*)d_out);
}